// Round 2
// baseline (13652.203 us; speedup 1.0000x reference)
//
#include <hip/hip_runtime.h>
#include <stdint.h>

typedef unsigned short u16;
typedef __attribute__((ext_vector_type(8))) _Float16 f16x8;
typedef __attribute__((ext_vector_type(4))) float f32x4;

// ---------- helpers ----------
__device__ inline f16x8 ldfrag(const u16* p) {
    return *(const f16x8*)p;   // 8 contiguous fp16 = 16B, alignment guaranteed by layout
}
__device__ inline u16 f2h(float x) {           // fp32 -> fp16 (RNE via hw convert)
    _Float16 h = (_Float16)x;
    union { _Float16 h; u16 u; } v; v.h = h;
    return v.u;
}
__device__ inline float sigmoidf_(float x) { return 1.0f / (1.0f + expf(-x)); }

// ---------- fused LSTM cell step ----------
// z = Xa @ Wa^T + Xb @ Wb^T + bsum ; gates(i,f,g,o) ; update c (fp32), h_out (fp16)
// grid: (4 m-tiles of 64 rows, 64 h-tiles of 16 cols) = 256 blocks; 4 waves = 4 gates.
// MFMA 16x16x32_f16: A lane: m=lane&15, k=(lane>>4)*8+j ; B lane: n=lane&15, same k
// D lane: col=lane&15, row=(lane>>4)*4+reg
__global__ __launch_bounds__(256) void lstm_cell_k(
    const u16* __restrict__ Xa, int Ka,          // (256 x Ka) fp16 row-major
    const u16* __restrict__ Wa,                  // (4096 x Ka) fp16 row-major
    const u16* __restrict__ Xb,                  // h_prev (256 x 1024) fp16
    const u16* __restrict__ Wb,                  // (4096 x 1024) fp16
    const float* __restrict__ bsum,              // (4096) = b_ih + b_hh
    float* __restrict__ c,                       // (256 x 1024) fp32, in/out
    u16* __restrict__ h_out)                     // (256 x 1024) fp16, out
{
    const int tid  = threadIdx.x;
    const int wave = tid >> 6;        // gate index: 0=i 1=f 2=g 3=o
    const int lane = tid & 63;
    const int l15  = lane & 15;
    const int quad = lane >> 4;
    const int m0   = blockIdx.x * 64;
    const int n0   = blockIdx.y * 16;

    f32x4 acc[4] = {{0,0,0,0},{0,0,0,0},{0,0,0,0},{0,0,0,0}};
    const int wrow = wave * 1024 + n0 + l15;     // row of W for this gate/col

    // phase A: x-side contribution
    {
        const u16* wp = Wa + (size_t)wrow * Ka + quad * 8;
        const u16* xr[4];
        #pragma unroll
        for (int t = 0; t < 4; ++t)
            xr[t] = Xa + (size_t)(m0 + 16 * t + l15) * Ka + quad * 8;
        #pragma unroll 2
        for (int k0 = 0; k0 < Ka; k0 += 32) {
            f16x8 b = ldfrag(wp + k0);
            #pragma unroll
            for (int t = 0; t < 4; ++t) {
                f16x8 a = ldfrag(xr[t] + k0);
                acc[t] = __builtin_amdgcn_mfma_f32_16x16x32_f16(a, b, acc[t], 0, 0, 0);
            }
        }
    }
    // phase B: h-side contribution (K = 1024)
    {
        const u16* wp = Wb + (size_t)wrow * 1024 + quad * 8;
        const u16* xr[4];
        #pragma unroll
        for (int t = 0; t < 4; ++t)
            xr[t] = Xb + (size_t)(m0 + 16 * t + l15) * 1024 + quad * 8;
        #pragma unroll 2
        for (int k0 = 0; k0 < 1024; k0 += 32) {
            f16x8 b = ldfrag(wp + k0);
            #pragma unroll
            for (int t = 0; t < 4; ++t) {
                f16x8 a = ldfrag(xr[t] + k0);
                acc[t] = __builtin_amdgcn_mfma_f32_16x16x32_f16(a, b, acc[t], 0, 0, 0);
            }
        }
    }

    // exchange gates via LDS (each wave holds one gate for the whole 64x16 tile)
    __shared__ float zsh[4][64][17];
    const float bv = bsum[wrow];
    #pragma unroll
    for (int t = 0; t < 4; ++t)
        #pragma unroll
        for (int r = 0; r < 4; ++r)
            zsh[wave][t * 16 + quad * 4 + r][l15] = acc[t][r] + bv;
    __syncthreads();

    #pragma unroll
    for (int e = tid; e < 64 * 16; e += 256) {
        const int row = e >> 4, col = e & 15;
        const float zi = zsh[0][row][col];
        const float zf = zsh[1][row][col];
        const float zg = zsh[2][row][col];
        const float zo = zsh[3][row][col];
        const size_t g = (size_t)(m0 + row) * 1024 + n0 + col;
        const float cv = c[g];
        const float cn = sigmoidf_(zf) * cv + sigmoidf_(zi) * tanhf(zg);
        c[g] = cn;
        h_out[g] = f2h(sigmoidf_(zo) * tanhf(cn));
    }
}

// ---------- FC layer 1: U = tanh(h1 @ fc_w1^T + b1), fp16 out ----------
// grid (4 m-tiles x 16 n-tiles of 64); wave w covers cols [64*by + 16w, +16)
__global__ __launch_bounds__(256) void fc1_k(
    const u16* __restrict__ X,      // (256 x 1024) fp16
    const u16* __restrict__ W,      // (1024 x 1024) fp16
    const float* __restrict__ bias, // (1024)
    u16* __restrict__ U)            // (256 x 1024) fp16
{
    const int tid  = threadIdx.x;
    const int wave = tid >> 6;
    const int lane = tid & 63;
    const int l15  = lane & 15;
    const int quad = lane >> 4;
    const int m0   = blockIdx.x * 64;
    const int n0   = blockIdx.y * 64 + wave * 16;

    f32x4 acc[4] = {{0,0,0,0},{0,0,0,0},{0,0,0,0},{0,0,0,0}};
    const u16* wp = W + (size_t)(n0 + l15) * 1024 + quad * 8;
    const u16* xr[4];
    #pragma unroll
    for (int t = 0; t < 4; ++t)
        xr[t] = X + (size_t)(m0 + 16 * t + l15) * 1024 + quad * 8;
    #pragma unroll 2
    for (int k0 = 0; k0 < 1024; k0 += 32) {
        f16x8 b = ldfrag(wp + k0);
        #pragma unroll
        for (int t = 0; t < 4; ++t) {
            f16x8 a = ldfrag(xr[t] + k0);
            acc[t] = __builtin_amdgcn_mfma_f32_16x16x32_f16(a, b, acc[t], 0, 0, 0);
        }
    }
    const float bv = bias[n0 + l15];
    #pragma unroll
    for (int t = 0; t < 4; ++t)
        #pragma unroll
        for (int r = 0; r < 4; ++r) {
            const int row = m0 + t * 16 + quad * 4 + r;
            U[(size_t)row * 1024 + n0 + l15] = f2h(tanhf(acc[t][r] + bv));
        }
}

// ---------- FC layer 2 + est feedback ----------
// est = U @ fc_w2^T + b2 + est_prev ; writes d_out slice (fp32), est_prev, x_dec est cols (fp16)
// grid (16 m-tiles of 16 rows); wave w covers cols [16w, +16) of 64
__global__ __launch_bounds__(256) void fc2_k(
    const u16* __restrict__ U,       // (256 x 1024) fp16
    const u16* __restrict__ W2,      // (64 x 1024) fp16
    const float* __restrict__ b2,    // (64)
    float* __restrict__ est_prev,    // (256 x 64) fp32 in/out (last_y carry)
    float* __restrict__ out_t,       // d_out + t*256*64
    u16* __restrict__ xdec_t)        // x_in_dec + t*256*256 (est cols at +192)
{
    const int tid  = threadIdx.x;
    const int wave = tid >> 6;
    const int lane = tid & 63;
    const int l15  = lane & 15;
    const int quad = lane >> 4;
    const int m0   = blockIdx.x * 16;
    const int col  = wave * 16 + l15;

    f32x4 acc = {0,0,0,0};
    const u16* wp = W2 + (size_t)col * 1024 + quad * 8;
    const u16* xp = U + (size_t)(m0 + l15) * 1024 + quad * 8;
    #pragma unroll 4
    for (int k0 = 0; k0 < 1024; k0 += 32)
        acc = __builtin_amdgcn_mfma_f32_16x16x32_f16(ldfrag(xp + k0), ldfrag(wp + k0), acc, 0, 0, 0);

    const float bv = b2[col];
    #pragma unroll
    for (int r = 0; r < 4; ++r) {
        const int row = m0 + quad * 4 + r;
        const float v = acc[r] + bv + est_prev[row * 64 + col];
        est_prev[row * 64 + col] = v;
        out_t[row * 64 + col] = v;
        xdec_t[row * 256 + 192 + col] = f2h(v);
    }
}

// ---------- setup kernels ----------
__global__ void cvt_k(const float* __restrict__ s, u16* __restrict__ d, int n) {
    int i = blockIdx.x * 256 + threadIdx.x;
    if (i < n) d[i] = f2h(s[i]);
}
__global__ void bias_k(const float* __restrict__ a, const float* __restrict__ b,
                       float* __restrict__ d, int n) {
    int i = blockIdx.x * 256 + threadIdx.x;
    if (i < n) d[i] = a[i] + b[i];
}
__global__ void init_k(u16* h0, u16* h1, float* c0, float* c1) {  // n = 256*1024
    int i = blockIdx.x * 256 + threadIdx.x;
    h0[i] = 0; h1[i] = 0; c0[i] = 0.0f; c1[i] = 0.0f;
}
__global__ void estinit_k(const float* __restrict__ pre_y, float* __restrict__ est_prev) {
    int i = blockIdx.x * 256 + threadIdx.x;   // n = 256*64
    est_prev[i] = pre_y[63 * 16384 + i];      // pre_y[-1]
}
__global__ void pack_enc_k(const float* __restrict__ pre_x, const float* __restrict__ pre_y,
                           u16* __restrict__ xy) {   // n = 64*256*256
    int i = blockIdx.x * 256 + threadIdx.x;
    int col = i & 255, tb = i >> 8;
    float v = (col < 192) ? pre_x[tb * 192 + col] : pre_y[tb * 64 + (col - 192)];
    xy[i] = f2h(v);
}
__global__ void pack_dec_k(const float* __restrict__ fx, u16* __restrict__ xd) { // n = 48*256*192
    int i = blockIdx.x * 256 + threadIdx.x;
    int col = i % 192, tb = i / 192;
    xd[tb * 256 + col] = f2h(fx[i]);
}

extern "C" void kernel_launch(void* const* d_in, const int* in_sizes, int n_in,
                              void* d_out, int out_size, void* d_ws, size_t ws_size,
                              hipStream_t stream) {
    const float* pre_x  = (const float*)d_in[0];
    const float* pre_y  = (const float*)d_in[1];
    const float* fx     = (const float*)d_in[2];
    const float* w_ih_0 = (const float*)d_in[3];
    const float* w_hh_0 = (const float*)d_in[4];
    const float* b_ih_0 = (const float*)d_in[5];
    const float* b_hh_0 = (const float*)d_in[6];
    const float* w_ih_1 = (const float*)d_in[7];
    const float* w_hh_1 = (const float*)d_in[8];
    const float* b_ih_1 = (const float*)d_in[9];
    const float* b_hh_1 = (const float*)d_in[10];
    const float* fc_w1  = (const float*)d_in[11];
    const float* fc_b1  = (const float*)d_in[12];
    const float* fc_w2  = (const float*)d_in[13];
    const float* fc_b2  = (const float*)d_in[14];

    size_t off = 0;
    char* wsb = (char*)d_ws;
    auto alloc = [&](size_t bytes) -> void* {
        void* p = wsb + off;
        off += (bytes + 255) & ~(size_t)255;
        return p;
    };
    u16* wih0 = (u16*)alloc((size_t)4096 * 256 * 2);
    u16* whh0 = (u16*)alloc((size_t)4096 * 1024 * 2);
    u16* wih1 = (u16*)alloc((size_t)4096 * 1024 * 2);
    u16* whh1 = (u16*)alloc((size_t)4096 * 1024 * 2);
    u16* fcw1 = (u16*)alloc((size_t)1024 * 1024 * 2);
    u16* fcw2 = (u16*)alloc((size_t)64 * 1024 * 2);
    float* b0s = (float*)alloc(4096 * 4);
    float* b1s = (float*)alloc(4096 * 4);
    u16* xyenc = (u16*)alloc((size_t)64 * 256 * 256 * 2);
    u16* xdec  = (u16*)alloc((size_t)48 * 256 * 256 * 2);
    u16* h0b[2] = { (u16*)alloc((size_t)256 * 1024 * 2), (u16*)alloc((size_t)256 * 1024 * 2) };
    u16* h1b[2] = { (u16*)alloc((size_t)256 * 1024 * 2), (u16*)alloc((size_t)256 * 1024 * 2) };
    float* c0 = (float*)alloc((size_t)256 * 1024 * 4);
    float* c1 = (float*)alloc((size_t)256 * 1024 * 4);
    u16* ufc  = (u16*)alloc((size_t)256 * 1024 * 2);
    float* estp = (float*)alloc((size_t)256 * 64 * 4);

    // --- setup: weight conversion, bias sums, state init, input packing ---
    cvt_k<<<(4096 * 256 + 255) / 256, 256, 0, stream>>>(w_ih_0, wih0, 4096 * 256);
    cvt_k<<<(4096 * 1024 + 255) / 256, 256, 0, stream>>>(w_hh_0, whh0, 4096 * 1024);
    cvt_k<<<(4096 * 1024 + 255) / 256, 256, 0, stream>>>(w_ih_1, wih1, 4096 * 1024);
    cvt_k<<<(4096 * 1024 + 255) / 256, 256, 0, stream>>>(w_hh_1, whh1, 4096 * 1024);
    cvt_k<<<(1024 * 1024 + 255) / 256, 256, 0, stream>>>(fc_w1, fcw1, 1024 * 1024);
    cvt_k<<<(64 * 1024 + 255) / 256, 256, 0, stream>>>(fc_w2, fcw2, 64 * 1024);
    bias_k<<<16, 256, 0, stream>>>(b_ih_0, b_hh_0, b0s, 4096);
    bias_k<<<16, 256, 0, stream>>>(b_ih_1, b_hh_1, b1s, 4096);
    init_k<<<1024, 256, 0, stream>>>(h0b[0], h1b[0], c0, c1);
    estinit_k<<<64, 256, 0, stream>>>(pre_y, estp);
    pack_enc_k<<<(64 * 256 * 256) / 256, 256, 0, stream>>>(pre_x, pre_y, xyenc);
    pack_dec_k<<<(48 * 256 * 192) / 256, 256, 0, stream>>>(fx, xdec);

    int cur = 0;
    // --- encode: 64 steps ---
    for (int t = 0; t < 64; ++t) {
        lstm_cell_k<<<dim3(4, 64), 256, 0, stream>>>(
            xyenc + (size_t)t * 256 * 256, 256, wih0, h0b[cur], whh0, b0s, c0, h0b[1 - cur]);
        lstm_cell_k<<<dim3(4, 64), 256, 0, stream>>>(
            h0b[1 - cur], 1024, wih1, h1b[cur], whh1, b1s, c1, h1b[1 - cur]);
        cur ^= 1;
    }
    // --- decode: 48 steps ---
    float* out = (float*)d_out;
    for (int t = 0; t < 48; ++t) {
        fc1_k<<<dim3(4, 16), 256, 0, stream>>>(h1b[cur], fcw1, fc_b1, ufc);
        fc2_k<<<dim3(16), 256, 0, stream>>>(ufc, fcw2, fc_b2, estp,
                                            out + (size_t)t * 16384,
                                            xdec + (size_t)t * 256 * 256);
        lstm_cell_k<<<dim3(4, 64), 256, 0, stream>>>(
            xdec + (size_t)t * 256 * 256, 256, wih0, h0b[cur], whh0, b0s, c0, h0b[1 - cur]);
        lstm_cell_k<<<dim3(4, 64), 256, 0, stream>>>(
            h0b[1 - cur], 1024, wih1, h1b[cur], whh1, b1s, c1, h1b[1 - cur]);
        cur ^= 1;
    }
}

// Round 3
// 5460.539 us; speedup vs baseline: 2.5002x; 2.5002x over previous
//
#include <hip/hip_runtime.h>
#include <stdint.h>

typedef unsigned short u16;
typedef __attribute__((ext_vector_type(8))) _Float16 f16x8;
typedef __attribute__((ext_vector_type(4))) float f32x4;

// ---------- helpers ----------
__device__ inline f16x8 ldfrag(const u16* p) { return *(const f16x8*)p; }
__device__ inline u16 f2h(float x) {
    _Float16 h = (_Float16)x;
    union { _Float16 h; u16 u; } v; v.h = h;
    return v.u;
}
__device__ inline float sigmoidf_(float x) { return 1.0f / (1.0f + expf(-x)); }

// Fragment layouts (all fp16 as u16):
//  A-frag (activations X: 256 rows x K):  AF[mtile][kb][lane][8], mtile=row>>4,
//      content = X[mtile*16 + (lane&15)][kb*32 + (lane>>4)*8 + j]
//  B-frag (weights W: N rows x K):        BF[ntile][kb][lane][8], ntile=wrow>>4,
//      content = W[ntile*16 + (lane&15)][kb*32 + (lane>>4)*8 + j]
// K-loop loads are then base + lane*16B : perfectly coalesced.

// ---------- fused LSTM cell step (no LDS, no barriers) ----------
// grid (64 col-tiles, 4 m-supers) x 256 thr; wave w -> mtile = by*4+w, all 4 gates.
// acc[g] = 16x16 tile of gate g at (mtile, coltile). D: col=lane&15, row=(lane>>4)*4+r.
__global__ __launch_bounds__(256) void lstm_cell_k(
    const u16* __restrict__ AFa, int KBa,        // x-side A-frags, KBa = Ka/32
    const u16* __restrict__ BFa,                 // w_ih B-frags (256 ntiles x KBa)
    const u16* __restrict__ AFh,                 // h_prev A-frags, KB=32
    const u16* __restrict__ BFh,                 // w_hh B-frags (256 ntiles x 32)
    const float* __restrict__ bsum,              // (4096)
    float* __restrict__ c,                       // (256x1024) fp32 row-major
    u16* __restrict__ h_out)                     // (256x1024) in A-frag layout
{
    const int tid  = threadIdx.x;
    const int w    = tid >> 6;
    const int lane = tid & 63;
    const int l15  = lane & 15;
    const int quad = lane >> 4;
    const int ct    = blockIdx.x;             // col-tile 0..63
    const int mtile = blockIdx.y * 4 + w;     // 0..15

    f32x4 acc[4] = {{0,0,0,0},{0,0,0,0},{0,0,0,0},{0,0,0,0}};

    // hoist bias loads (overlap with K-loop)
    float bv[4];
    #pragma unroll
    for (int g = 0; g < 4; ++g) bv[g] = bsum[g * 1024 + ct * 16 + l15];

    // phase A: x-side
    {
        const u16* ap = AFa + ((size_t)(mtile * KBa) * 64 + lane) * 8;
        const u16* bp[4];
        #pragma unroll
        for (int g = 0; g < 4; ++g)
            bp[g] = BFa + ((size_t)((g * 64 + ct) * KBa) * 64 + lane) * 8;
        #pragma unroll 4
        for (int kb = 0; kb < KBa; ++kb) {
            f16x8 a = ldfrag(ap + kb * 512);
            #pragma unroll
            for (int g = 0; g < 4; ++g)
                acc[g] = __builtin_amdgcn_mfma_f32_16x16x32_f16(a, ldfrag(bp[g] + kb * 512), acc[g], 0, 0, 0);
        }
    }
    // phase B: h-side (KB = 32)
    {
        const u16* ap = AFh + ((size_t)(mtile * 32) * 64 + lane) * 8;
        const u16* bp[4];
        #pragma unroll
        for (int g = 0; g < 4; ++g)
            bp[g] = BFh + ((size_t)((g * 64 + ct) * 32) * 64 + lane) * 8;
        #pragma unroll 4
        for (int kb = 0; kb < 32; ++kb) {
            f16x8 a = ldfrag(ap + kb * 512);
            #pragma unroll
            for (int g = 0; g < 4; ++g)
                acc[g] = __builtin_amdgcn_mfma_f32_16x16x32_f16(a, ldfrag(bp[g] + kb * 512), acc[g], 0, 0, 0);
        }
    }

    // epilogue: all 4 gates for (row,col) live in this lane
    const int col = ct * 16 + l15;
    const int hkb = col >> 5, hquad = (col >> 3) & 3, hj = col & 7;
    #pragma unroll
    for (int r = 0; r < 4; ++r) {
        const int rl = quad * 4 + r;              // row within mtile
        const int row = mtile * 16 + rl;
        const size_t gi = (size_t)row * 1024 + col;
        const float zi = acc[0][r] + bv[0];
        const float zf = acc[1][r] + bv[1];
        const float zg = acc[2][r] + bv[2];
        const float zo = acc[3][r] + bv[3];
        const float cv = c[gi];
        const float cn = sigmoidf_(zf) * cv + sigmoidf_(zi) * tanhf(zg);
        c[gi] = cn;
        h_out[(((size_t)mtile * 32 + hkb) * 64 + hquad * 16 + rl) * 8 + hj] =
            f2h(sigmoidf_(zo) * tanhf(cn));
    }
}

// ---------- FC layer 1: U = tanh(h1 @ fc_w1^T + b1) ----------
// 1024 tiles (16 mt x 64 nt); grid 256 blocks x 4 waves, 1 tile/wave.
__global__ __launch_bounds__(256) void fc1_k(
    const u16* __restrict__ AFx,     // h1 A-frags (KB=32)
    const u16* __restrict__ BFw,     // fc_w1 B-frags (64 ntiles x 32)
    const float* __restrict__ bias,
    u16* __restrict__ U)             // (256x1024) A-frag layout
{
    const int tid  = threadIdx.x;
    const int w    = tid >> 6;
    const int lane = tid & 63;
    const int l15  = lane & 15;
    const int quad = lane >> 4;
    const int tile = blockIdx.x * 4 + w;
    const int mtile = tile >> 6, ntile = tile & 63;

    f32x4 accp[4] = {{0,0,0,0},{0,0,0,0},{0,0,0,0},{0,0,0,0}};
    const u16* ap = AFx + ((size_t)(mtile * 32) * 64 + lane) * 8;
    const u16* bp = BFw + ((size_t)(ntile * 32) * 64 + lane) * 8;
    #pragma unroll 4
    for (int kb = 0; kb < 32; ++kb)
        accp[kb & 3] = __builtin_amdgcn_mfma_f32_16x16x32_f16(
            ldfrag(ap + kb * 512), ldfrag(bp + kb * 512), accp[kb & 3], 0, 0, 0);
    f32x4 acc = accp[0] + accp[1] + accp[2] + accp[3];

    const int col = ntile * 16 + l15;
    const float bv = bias[col];
    const int ukb = col >> 5, uquad = (col >> 3) & 3, uj = col & 7;
    #pragma unroll
    for (int r = 0; r < 4; ++r) {
        const int rl = quad * 4 + r;
        U[(((size_t)mtile * 32 + ukb) * 64 + uquad * 16 + rl) * 8 + uj] =
            f2h(tanhf(acc[r] + bv));
    }
}

// ---------- FC layer 2 + est feedback ----------
// grid 16 blocks (m-tiles) x 4 waves (n-tiles of 16 of the 64 out cols)
__global__ __launch_bounds__(256) void fc2_k(
    const u16* __restrict__ AFu,     // U A-frags (KB=32)
    const u16* __restrict__ BFw2,    // fc_w2 B-frags (4 ntiles x 32)
    const float* __restrict__ b2,
    float* __restrict__ est_prev,    // (256x64) fp32
    float* __restrict__ out_t,       // d_out + t*16384
    u16* __restrict__ xdec_t)        // xdec A-frag block for step t (est cols 192..255)
{
    const int tid  = threadIdx.x;
    const int w    = tid >> 6;
    const int lane = tid & 63;
    const int l15  = lane & 15;
    const int quad = lane >> 4;
    const int mtile = blockIdx.x;

    f32x4 accp[4] = {{0,0,0,0},{0,0,0,0},{0,0,0,0},{0,0,0,0}};
    const u16* ap = AFu + ((size_t)(mtile * 32) * 64 + lane) * 8;
    const u16* bp = BFw2 + ((size_t)(w * 32) * 64 + lane) * 8;
    #pragma unroll 4
    for (int kb = 0; kb < 32; ++kb)
        accp[kb & 3] = __builtin_amdgcn_mfma_f32_16x16x32_f16(
            ldfrag(ap + kb * 512), ldfrag(bp + kb * 512), accp[kb & 3], 0, 0, 0);
    f32x4 acc = accp[0] + accp[1] + accp[2] + accp[3];

    const int col = w * 16 + l15;            // 0..63
    const float bv = b2[col];
    const int cx = 192 + col;                // column in dec input
    const int xkb = cx >> 5, xquad = (cx >> 3) & 3, xj = cx & 7;
    #pragma unroll
    for (int r = 0; r < 4; ++r) {
        const int rl = quad * 4 + r;
        const int row = mtile * 16 + rl;
        const float v = acc[r] + bv + est_prev[row * 64 + col];
        est_prev[row * 64 + col] = v;
        out_t[row * 64 + col] = v;
        xdec_t[(((size_t)mtile * 8 + xkb) * 64 + xquad * 16 + rl) * 8 + xj] = f2h(v);
    }
}

// ---------- setup kernels ----------
// fp32 row-major (N x K) -> B-frag fp16. One thread per 8 elems.
__global__ void cvt_bfrag_k(const float* __restrict__ src, u16* __restrict__ dst,
                            int K, int kbshift, int total_threads) {
    int i = blockIdx.x * 256 + threadIdx.x;
    if (i >= total_threads) return;
    const int lane = i & 63;
    const int kb   = (i >> 6) & ((1 << kbshift) - 1);
    const int nt   = i >> (6 + kbshift);
    const int row  = nt * 16 + (lane & 15);
    const int col  = kb * 32 + (lane >> 4) * 8;
    const float* s = src + (size_t)row * K + col;
    u16* d = dst + (size_t)i * 8;
    #pragma unroll
    for (int j = 0; j < 8; ++j) d[j] = f2h(s[j]);
}
__global__ void bias_k(const float* __restrict__ a, const float* __restrict__ b,
                       float* __restrict__ d, int n) {
    int i = blockIdx.x * 256 + threadIdx.x;
    if (i < n) d[i] = a[i] + b[i];
}
__global__ void init_k(u16* h0, u16* h1, float* c0, float* c1) {  // n = 256*1024
    int i = blockIdx.x * 256 + threadIdx.x;
    h0[i] = 0; h1[i] = 0; c0[i] = 0.0f; c1[i] = 0.0f;
}
__global__ void estinit_k(const float* __restrict__ pre_y, float* __restrict__ est_prev) {
    int i = blockIdx.x * 256 + threadIdx.x;   // n = 256*64
    est_prev[i] = pre_y[63 * 16384 + i];      // pre_y[-1]
}
// enc input (PRE_LEN,B,IN) -> per-t A-frag blocks (16 mt x 8 kb x 64 x 8)
__global__ void pack_enc_k(const float* __restrict__ pre_x, const float* __restrict__ pre_y,
                           u16* __restrict__ xy) {   // threads = 64*16*8*64
    int i = blockIdx.x * 256 + threadIdx.x;
    const int lane  = i & 63;
    const int kb    = (i >> 6) & 7;
    const int mtile = (i >> 9) & 15;
    const int t     = i >> 13;
    const int row   = mtile * 16 + (lane & 15);
    const int cb    = kb * 32 + (lane >> 4) * 8;
    u16* d = xy + (size_t)i * 8;
    #pragma unroll
    for (int j = 0; j < 8; ++j) {
        const int col = cb + j;
        const float v = (col < 192) ? pre_x[((size_t)t * 256 + row) * 192 + col]
                                    : pre_y[((size_t)t * 256 + row) * 64 + (col - 192)];
        d[j] = f2h(v);
    }
}
// dec exo input: fills kb 0..5 (cols 0..191) of each step's A-frag block
__global__ void pack_dec_k(const float* __restrict__ fx, u16* __restrict__ xd,
                           int total_threads) {      // threads = 48*16*6*64
    int i = blockIdx.x * 256 + threadIdx.x;
    if (i >= total_threads) return;
    const int lane  = i & 63;
    int rest = i >> 6;
    const int kb    = rest % 6;  rest /= 6;
    const int mtile = rest & 15;
    const int t     = rest >> 4;
    const int row   = mtile * 16 + (lane & 15);
    const int cb    = kb * 32 + (lane >> 4) * 8;
    u16* d = xd + ((((size_t)t * 16 + mtile) * 8 + kb) * 64 + lane) * 8;
    #pragma unroll
    for (int j = 0; j < 8; ++j)
        d[j] = f2h(fx[((size_t)t * 256 + row) * 192 + cb + j]);
}

extern "C" void kernel_launch(void* const* d_in, const int* in_sizes, int n_in,
                              void* d_out, int out_size, void* d_ws, size_t ws_size,
                              hipStream_t stream) {
    const float* pre_x  = (const float*)d_in[0];
    const float* pre_y  = (const float*)d_in[1];
    const float* fx     = (const float*)d_in[2];
    const float* w_ih_0 = (const float*)d_in[3];
    const float* w_hh_0 = (const float*)d_in[4];
    const float* b_ih_0 = (const float*)d_in[5];
    const float* b_hh_0 = (const float*)d_in[6];
    const float* w_ih_1 = (const float*)d_in[7];
    const float* w_hh_1 = (const float*)d_in[8];
    const float* b_ih_1 = (const float*)d_in[9];
    const float* b_hh_1 = (const float*)d_in[10];
    const float* fc_w1  = (const float*)d_in[11];
    const float* fc_b1  = (const float*)d_in[12];
    const float* fc_w2  = (const float*)d_in[13];
    const float* fc_b2  = (const float*)d_in[14];

    size_t off = 0;
    char* wsb = (char*)d_ws;
    auto alloc = [&](size_t bytes) -> void* {
        void* p = wsb + off;
        off += (bytes + 255) & ~(size_t)255;
        return p;
    };
    u16* wih0 = (u16*)alloc((size_t)4096 * 256 * 2);
    u16* whh0 = (u16*)alloc((size_t)4096 * 1024 * 2);
    u16* wih1 = (u16*)alloc((size_t)4096 * 1024 * 2);
    u16* whh1 = (u16*)alloc((size_t)4096 * 1024 * 2);
    u16* fcw1 = (u16*)alloc((size_t)1024 * 1024 * 2);
    u16* fcw2 = (u16*)alloc((size_t)64 * 1024 * 2);
    float* b0s = (float*)alloc(4096 * 4);
    float* b1s = (float*)alloc(4096 * 4);
    u16* xyenc = (u16*)alloc((size_t)64 * 256 * 256 * 2);
    u16* xdec  = (u16*)alloc((size_t)48 * 256 * 256 * 2);
    u16* h0b[2] = { (u16*)alloc((size_t)256 * 1024 * 2), (u16*)alloc((size_t)256 * 1024 * 2) };
    u16* h1b[2] = { (u16*)alloc((size_t)256 * 1024 * 2), (u16*)alloc((size_t)256 * 1024 * 2) };
    float* c0 = (float*)alloc((size_t)256 * 1024 * 4);
    float* c1 = (float*)alloc((size_t)256 * 1024 * 4);
    u16* ufc  = (u16*)alloc((size_t)256 * 1024 * 2);
    float* estp = (float*)alloc((size_t)256 * 64 * 4);

    // --- setup: weight reorder to frag layout, bias sums, state init, packing ---
    cvt_bfrag_k<<<512, 256, 0, stream>>>(w_ih_0, wih0, 256, 3, 256 * 8 * 64);
    cvt_bfrag_k<<<2048, 256, 0, stream>>>(w_hh_0, whh0, 1024, 5, 256 * 32 * 64);
    cvt_bfrag_k<<<2048, 256, 0, stream>>>(w_ih_1, wih1, 1024, 5, 256 * 32 * 64);
    cvt_bfrag_k<<<2048, 256, 0, stream>>>(w_hh_1, whh1, 1024, 5, 256 * 32 * 64);
    cvt_bfrag_k<<<512, 256, 0, stream>>>(fc_w1, fcw1, 1024, 5, 64 * 32 * 64);
    cvt_bfrag_k<<<32, 256, 0, stream>>>(fc_w2, fcw2, 1024, 5, 4 * 32 * 64);
    bias_k<<<16, 256, 0, stream>>>(b_ih_0, b_hh_0, b0s, 4096);
    bias_k<<<16, 256, 0, stream>>>(b_ih_1, b_hh_1, b1s, 4096);
    init_k<<<1024, 256, 0, stream>>>(h0b[0], h1b[0], c0, c1);
    estinit_k<<<64, 256, 0, stream>>>(pre_y, estp);
    pack_enc_k<<<2048, 256, 0, stream>>>(pre_x, pre_y, xyenc);
    pack_dec_k<<<1152, 256, 0, stream>>>(fx, xdec, 48 * 16 * 6 * 64);

    int cur = 0;
    // --- encode: 64 steps ---
    for (int t = 0; t < 64; ++t) {
        lstm_cell_k<<<dim3(64, 4), 256, 0, stream>>>(
            xyenc + (size_t)t * 65536, 8, wih0, h0b[cur], whh0, b0s, c0, h0b[1 - cur]);
        lstm_cell_k<<<dim3(64, 4), 256, 0, stream>>>(
            h0b[1 - cur], 32, wih1, h1b[cur], whh1, b1s, c1, h1b[1 - cur]);
        cur ^= 1;
    }
    // --- decode: 48 steps ---
    float* out = (float*)d_out;
    for (int t = 0; t < 48; ++t) {
        fc1_k<<<256, 256, 0, stream>>>(h1b[cur], fcw1, fc_b1, ufc);
        fc2_k<<<16, 256, 0, stream>>>(ufc, fcw2, fc_b2, estp,
                                      out + (size_t)t * 16384,
                                      xdec + (size_t)t * 65536);
        lstm_cell_k<<<dim3(64, 4), 256, 0, stream>>>(
            xdec + (size_t)t * 65536, 8, wih0, h0b[cur], whh0, b0s, c0, h0b[1 - cur]);
        lstm_cell_k<<<dim3(64, 4), 256, 0, stream>>>(
            h0b[1 - cur], 32, wih1, h1b[cur], whh1, b1s, c1, h1b[1 - cur]);
        cur ^= 1;
    }
}

// Round 4
// 4010.597 us; speedup vs baseline: 3.4040x; 1.3615x over previous
//
#include <hip/hip_runtime.h>
#include <stdint.h>

typedef unsigned short u16;
typedef __attribute__((ext_vector_type(8))) _Float16 f16x8;
typedef __attribute__((ext_vector_type(4))) float f32x4;

// ---------- helpers ----------
__device__ inline f16x8 ldfrag(const u16* p) { return *(const f16x8*)p; }
__device__ inline u16 f2h(float x) {
    _Float16 h = (_Float16)x;
    union { _Float16 h; u16 u; } v; v.h = h;
    return v.u;
}
__device__ inline float sigmoidf_(float x) { return 1.0f / (1.0f + expf(-x)); }

// Layouts (fp16 as u16):
//  A-frag (X: 256 x K):  AF[mtile][kb][lane][8]
//      = X[mtile*16 + (lane&15)][kb*32 + (lane>>4)*8 + j]
//  B-frag (W: N x K):    BF[grp][sub][kb][lane][8]
//      = W[row(grp,sub,lane)][kb*32 + (lane>>4)*8 + j],  row = sub*S1 + grp*S2 + (lane&15)
//  lstm:  S1=1024 (gate), S2=16 (ct)   -> BF[ct][gate][kb][..]
//  fc1:   S1=16,  S2=64                -> BF[ctq][nt ][kb][..]
//  fc2:   S1=16,  S2=0 (grp=0)         -> BF[0][nt][kb][..]

// ---------- fused LSTM cell step ----------
// grid (64 ct, 4 mg) = 256 blocks; wave w: 4 mt x 4 gates, K-quarter w.
// Cross-wave K-reduction via LDS; epilogue in-lane (all 4 gates per (row,col)).
__global__ __launch_bounds__(256, 1) void lstm_cell_k(
    const u16* __restrict__ AFa, int KBa,        // x-side A-frags, KBa = Ka/32
    const u16* __restrict__ BFa,                 // w_ih  [64][4][KBa][64][8]
    const u16* __restrict__ AFh,                 // h_prev A-frags (KB=32)
    const u16* __restrict__ BFh,                 // w_hh  [64][4][32][64][8]
    const float* __restrict__ bsum,              // (4096)
    float* __restrict__ c,                       // (256x1024) fp32 row-major
    u16* __restrict__ h_out)                     // (256x1024) A-frag layout
{
    const int tid  = threadIdx.x;
    const int w    = tid >> 6;
    const int lane = tid & 63;
    const int l15  = lane & 15;
    const int quad = lane >> 4;
    const int ct   = blockIdx.x;     // 0..63
    const int mg   = blockIdx.y;     // 0..3

    f32x4 acc[4][4];
    #pragma unroll
    for (int t = 0; t < 4; ++t)
        #pragma unroll
        for (int g = 0; g < 4; ++g) acc[t][g] = (f32x4){0, 0, 0, 0};

    // phase A: x-side, wave w takes kb in [w*q, w*q+q)
    {
        const int q = KBa >> 2;
        #pragma unroll 2
        for (int kb = w * q; kb < w * q + q; ++kb) {
            f16x8 a[4], b[4];
            #pragma unroll
            for (int t = 0; t < 4; ++t)
                a[t] = ldfrag(AFa + (((size_t)(mg * 4 + t) * KBa + kb) * 64 + lane) * 8);
            #pragma unroll
            for (int g = 0; g < 4; ++g)
                b[g] = ldfrag(BFa + (((size_t)(ct * 4 + g) * KBa + kb) * 64 + lane) * 8);
            #pragma unroll
            for (int t = 0; t < 4; ++t)
                #pragma unroll
                for (int g = 0; g < 4; ++g)
                    acc[t][g] = __builtin_amdgcn_mfma_f32_16x16x32_f16(a[t], b[g], acc[t][g], 0, 0, 0);
        }
    }
    // phase B: h-side, KB=32, quarter = 8
    {
        #pragma unroll 2
        for (int kb = w * 8; kb < w * 8 + 8; ++kb) {
            f16x8 a[4], b[4];
            #pragma unroll
            for (int t = 0; t < 4; ++t)
                a[t] = ldfrag(AFh + (((size_t)(mg * 4 + t) * 32 + kb) * 64 + lane) * 8);
            #pragma unroll
            for (int g = 0; g < 4; ++g)
                b[g] = ldfrag(BFh + (((size_t)(ct * 4 + g) * 32 + kb) * 64 + lane) * 8);
            #pragma unroll
            for (int t = 0; t < 4; ++t)
                #pragma unroll
                for (int g = 0; g < 4; ++g)
                    acc[t][g] = __builtin_amdgcn_mfma_f32_16x16x32_f16(a[t], b[g], acc[t][g], 0, 0, 0);
        }
    }

    // cross-wave K-reduction
    __shared__ f32x4 red[4][16][64];
    #pragma unroll
    for (int t = 0; t < 4; ++t)
        #pragma unroll
        for (int g = 0; g < 4; ++g)
            red[w][t * 4 + g][lane] = acc[t][g];
    __syncthreads();

    // wave w owns mt = mg*4 + w
    f32x4 z[4];
    #pragma unroll
    for (int g = 0; g < 4; ++g)
        z[g] = red[0][w * 4 + g][lane] + red[1][w * 4 + g][lane] +
               red[2][w * 4 + g][lane] + red[3][w * 4 + g][lane];

    const int col   = ct * 16 + l15;
    const int mtile = mg * 4 + w;
    float bv[4];
    #pragma unroll
    for (int g = 0; g < 4; ++g) bv[g] = bsum[g * 1024 + col];
    const int hkb = col >> 5, hquad = (col >> 3) & 3, hj = col & 7;
    #pragma unroll
    for (int r = 0; r < 4; ++r) {
        const int rl  = quad * 4 + r;
        const int row = mtile * 16 + rl;
        const size_t gi = (size_t)row * 1024 + col;
        const float zi = z[0][r] + bv[0];
        const float zf = z[1][r] + bv[1];
        const float zg = z[2][r] + bv[2];
        const float zo = z[3][r] + bv[3];
        const float cv = c[gi];
        const float cn = sigmoidf_(zf) * cv + sigmoidf_(zi) * tanhf(zg);
        c[gi] = cn;
        h_out[(((size_t)mtile * 32 + hkb) * 64 + hquad * 16 + rl) * 8 + hj] =
            f2h(sigmoidf_(zo) * tanhf(cn));
    }
}

// ---------- FC layer 1: U = tanh(h1 @ fc_w1^T + b1) ----------
// grid (16 ctq, 4 mg) = 64 blocks; wave w: 4 mt x 4 nt, K-quarter w.
__global__ __launch_bounds__(256, 1) void fc1_k(
    const u16* __restrict__ AFx,     // h1 A-frags (KB=32)
    const u16* __restrict__ BFw,     // fc_w1 [16][4][32][64][8]
    const float* __restrict__ bias,
    u16* __restrict__ U)             // (256x1024) A-frag layout
{
    const int tid  = threadIdx.x;
    const int w    = tid >> 6;
    const int lane = tid & 63;
    const int l15  = lane & 15;
    const int quad = lane >> 4;
    const int ctq  = blockIdx.x;     // 0..15
    const int mg   = blockIdx.y;     // 0..3

    f32x4 acc[4][4];
    #pragma unroll
    for (int t = 0; t < 4; ++t)
        #pragma unroll
        for (int g = 0; g < 4; ++g) acc[t][g] = (f32x4){0, 0, 0, 0};

    #pragma unroll 2
    for (int kb = w * 8; kb < w * 8 + 8; ++kb) {
        f16x8 a[4], b[4];
        #pragma unroll
        for (int t = 0; t < 4; ++t)
            a[t] = ldfrag(AFx + (((size_t)(mg * 4 + t) * 32 + kb) * 64 + lane) * 8);
        #pragma unroll
        for (int g = 0; g < 4; ++g)
            b[g] = ldfrag(BFw + (((size_t)(ctq * 4 + g) * 32 + kb) * 64 + lane) * 8);
        #pragma unroll
        for (int t = 0; t < 4; ++t)
            #pragma unroll
            for (int g = 0; g < 4; ++g)
                acc[t][g] = __builtin_amdgcn_mfma_f32_16x16x32_f16(a[t], b[g], acc[t][g], 0, 0, 0);
    }

    __shared__ f32x4 red[4][16][64];
    #pragma unroll
    for (int t = 0; t < 4; ++t)
        #pragma unroll
        for (int g = 0; g < 4; ++g)
            red[w][t * 4 + g][lane] = acc[t][g];
    __syncthreads();

    f32x4 z[4];
    #pragma unroll
    for (int g = 0; g < 4; ++g)
        z[g] = red[0][w * 4 + g][lane] + red[1][w * 4 + g][lane] +
               red[2][w * 4 + g][lane] + red[3][w * 4 + g][lane];

    const int mtile = mg * 4 + w;
    #pragma unroll
    for (int g = 0; g < 4; ++g) {
        const int col = ctq * 64 + g * 16 + l15;
        const float bv = bias[col];
        const int ukb = col >> 5, uquad = (col >> 3) & 3, uj = col & 7;
        #pragma unroll
        for (int r = 0; r < 4; ++r) {
            const int rl = quad * 4 + r;
            U[(((size_t)mtile * 32 + ukb) * 64 + uquad * 16 + rl) * 8 + uj] =
                f2h(tanhf(z[g][r] + bv));
        }
    }
}

// ---------- FC layer 2 + est feedback ----------
__global__ __launch_bounds__(256) void fc2_k(
    const u16* __restrict__ AFu,     // U A-frags (KB=32)
    const u16* __restrict__ BFw2,    // fc_w2 [0][4][32][64][8]
    const float* __restrict__ b2,
    float* __restrict__ est_prev,    // (256x64) fp32
    float* __restrict__ out_t,       // d_out + t*16384
    u16* __restrict__ xdec_t)        // xdec A-frag block for step t
{
    const int tid  = threadIdx.x;
    const int w    = tid >> 6;
    const int lane = tid & 63;
    const int l15  = lane & 15;
    const int quad = lane >> 4;
    const int mtile = blockIdx.x;

    f32x4 accp[4] = {{0,0,0,0},{0,0,0,0},{0,0,0,0},{0,0,0,0}};
    const u16* ap = AFu + ((size_t)(mtile * 32) * 64 + lane) * 8;
    const u16* bp = BFw2 + ((size_t)(w * 32) * 64 + lane) * 8;
    #pragma unroll 4
    for (int kb = 0; kb < 32; ++kb)
        accp[kb & 3] = __builtin_amdgcn_mfma_f32_16x16x32_f16(
            ldfrag(ap + kb * 512), ldfrag(bp + kb * 512), accp[kb & 3], 0, 0, 0);
    f32x4 acc = accp[0] + accp[1] + accp[2] + accp[3];

    const int col = w * 16 + l15;
    const float bv = b2[col];
    const int cx = 192 + col;
    const int xkb = cx >> 5, xquad = (cx >> 3) & 3, xj = cx & 7;
    #pragma unroll
    for (int r = 0; r < 4; ++r) {
        const int rl = quad * 4 + r;
        const int row = mtile * 16 + rl;
        const float v = acc[r] + bv + est_prev[row * 64 + col];
        est_prev[row * 64 + col] = v;
        out_t[row * 64 + col] = v;
        xdec_t[(((size_t)mtile * 8 + xkb) * 64 + xquad * 16 + rl) * 8 + xj] = f2h(v);
    }
}

// ---------- setup kernels ----------
// fp32 (N x K) -> B-frag [grp][sub][kb][lane][8]; row = sub*S1 + grp*S2 + (lane&15)
__global__ void cvt_bfrag_k(const float* __restrict__ src, u16* __restrict__ dst,
                            int K, int kbshift, int S1, int S2, int total) {
    int i = blockIdx.x * 256 + threadIdx.x;
    if (i >= total) return;
    const int lane = i & 63;
    const int kb   = (i >> 6) & ((1 << kbshift) - 1);
    const int rest = i >> (6 + kbshift);
    const int sub  = rest & 3;
    const int grp  = rest >> 2;
    const int row  = sub * S1 + grp * S2 + (lane & 15);
    const int colK = kb * 32 + (lane >> 4) * 8;
    const float* s = src + (size_t)row * K + colK;
    u16* d = dst + (size_t)i * 8;
    #pragma unroll
    for (int j = 0; j < 8; ++j) d[j] = f2h(s[j]);
}
__global__ void bias_k(const float* __restrict__ a, const float* __restrict__ b,
                       float* __restrict__ d, int n) {
    int i = blockIdx.x * 256 + threadIdx.x;
    if (i < n) d[i] = a[i] + b[i];
}
__global__ void init_k(u16* h0, u16* h1, float* c0, float* c1) {  // n = 256*1024
    int i = blockIdx.x * 256 + threadIdx.x;
    h0[i] = 0; h1[i] = 0; c0[i] = 0.0f; c1[i] = 0.0f;
}
__global__ void estinit_k(const float* __restrict__ pre_y, float* __restrict__ est_prev) {
    int i = blockIdx.x * 256 + threadIdx.x;   // n = 256*64
    est_prev[i] = pre_y[63 * 16384 + i];      // pre_y[-1]
}
__global__ void pack_enc_k(const float* __restrict__ pre_x, const float* __restrict__ pre_y,
                           u16* __restrict__ xy) {   // threads = 64*16*8*64
    int i = blockIdx.x * 256 + threadIdx.x;
    const int lane  = i & 63;
    const int kb    = (i >> 6) & 7;
    const int mtile = (i >> 9) & 15;
    const int t     = i >> 13;
    const int row   = mtile * 16 + (lane & 15);
    const int cb    = kb * 32 + (lane >> 4) * 8;
    u16* d = xy + (size_t)i * 8;
    #pragma unroll
    for (int j = 0; j < 8; ++j) {
        const int col = cb + j;
        const float v = (col < 192) ? pre_x[((size_t)t * 256 + row) * 192 + col]
                                    : pre_y[((size_t)t * 256 + row) * 64 + (col - 192)];
        d[j] = f2h(v);
    }
}
__global__ void pack_dec_k(const float* __restrict__ fx, u16* __restrict__ xd,
                           int total_threads) {      // threads = 48*16*6*64
    int i = blockIdx.x * 256 + threadIdx.x;
    if (i >= total_threads) return;
    const int lane  = i & 63;
    int rest = i >> 6;
    const int kb    = rest % 6;  rest /= 6;
    const int mtile = rest & 15;
    const int t     = rest >> 4;
    const int row   = mtile * 16 + (lane & 15);
    const int cb    = kb * 32 + (lane >> 4) * 8;
    u16* d = xd + ((((size_t)t * 16 + mtile) * 8 + kb) * 64 + lane) * 8;
    #pragma unroll
    for (int j = 0; j < 8; ++j)
        d[j] = f2h(fx[((size_t)t * 256 + row) * 192 + cb + j]);
}

extern "C" void kernel_launch(void* const* d_in, const int* in_sizes, int n_in,
                              void* d_out, int out_size, void* d_ws, size_t ws_size,
                              hipStream_t stream) {
    const float* pre_x  = (const float*)d_in[0];
    const float* pre_y  = (const float*)d_in[1];
    const float* fx     = (const float*)d_in[2];
    const float* w_ih_0 = (const float*)d_in[3];
    const float* w_hh_0 = (const float*)d_in[4];
    const float* b_ih_0 = (const float*)d_in[5];
    const float* b_hh_0 = (const float*)d_in[6];
    const float* w_ih_1 = (const float*)d_in[7];
    const float* w_hh_1 = (const float*)d_in[8];
    const float* b_ih_1 = (const float*)d_in[9];
    const float* b_hh_1 = (const float*)d_in[10];
    const float* fc_w1  = (const float*)d_in[11];
    const float* fc_b1  = (const float*)d_in[12];
    const float* fc_w2  = (const float*)d_in[13];
    const float* fc_b2  = (const float*)d_in[14];

    size_t off = 0;
    char* wsb = (char*)d_ws;
    auto alloc = [&](size_t bytes) -> void* {
        void* p = wsb + off;
        off += (bytes + 255) & ~(size_t)255;
        return p;
    };
    u16* wih0 = (u16*)alloc((size_t)4096 * 256 * 2);
    u16* whh0 = (u16*)alloc((size_t)4096 * 1024 * 2);
    u16* wih1 = (u16*)alloc((size_t)4096 * 1024 * 2);
    u16* whh1 = (u16*)alloc((size_t)4096 * 1024 * 2);
    u16* fcw1 = (u16*)alloc((size_t)1024 * 1024 * 2);
    u16* fcw2 = (u16*)alloc((size_t)64 * 1024 * 2);
    float* b0s = (float*)alloc(4096 * 4);
    float* b1s = (float*)alloc(4096 * 4);
    u16* xyenc = (u16*)alloc((size_t)64 * 256 * 256 * 2);
    u16* xdec  = (u16*)alloc((size_t)48 * 256 * 256 * 2);
    u16* h0b[2] = { (u16*)alloc((size_t)256 * 1024 * 2), (u16*)alloc((size_t)256 * 1024 * 2) };
    u16* h1b[2] = { (u16*)alloc((size_t)256 * 1024 * 2), (u16*)alloc((size_t)256 * 1024 * 2) };
    float* c0 = (float*)alloc((size_t)256 * 1024 * 4);
    float* c1 = (float*)alloc((size_t)256 * 1024 * 4);
    u16* ufc  = (u16*)alloc((size_t)256 * 1024 * 2);
    float* estp = (float*)alloc((size_t)256 * 64 * 4);

    // --- setup ---
    // lstm B layout: S1=1024 (gate), S2=16 (ct)
    cvt_bfrag_k<<<512, 256, 0, stream>>>(w_ih_0, wih0, 256, 3, 1024, 16, 64 * 4 * 8 * 64);
    cvt_bfrag_k<<<2048, 256, 0, stream>>>(w_hh_0, whh0, 1024, 5, 1024, 16, 64 * 4 * 32 * 64);
    cvt_bfrag_k<<<2048, 256, 0, stream>>>(w_ih_1, wih1, 1024, 5, 1024, 16, 64 * 4 * 32 * 64);
    cvt_bfrag_k<<<2048, 256, 0, stream>>>(w_hh_1, whh1, 1024, 5, 1024, 16, 64 * 4 * 32 * 64);
    // fc1 B layout: S1=16 (nt), S2=64 (ctq)
    cvt_bfrag_k<<<512, 256, 0, stream>>>(fc_w1, fcw1, 1024, 5, 16, 64, 16 * 4 * 32 * 64);
    // fc2 B layout: S1=16, grp=0
    cvt_bfrag_k<<<32, 256, 0, stream>>>(fc_w2, fcw2, 1024, 5, 16, 0, 1 * 4 * 32 * 64);
    bias_k<<<16, 256, 0, stream>>>(b_ih_0, b_hh_0, b0s, 4096);
    bias_k<<<16, 256, 0, stream>>>(b_ih_1, b_hh_1, b1s, 4096);
    init_k<<<1024, 256, 0, stream>>>(h0b[0], h1b[0], c0, c1);
    estinit_k<<<64, 256, 0, stream>>>(pre_y, estp);
    pack_enc_k<<<2048, 256, 0, stream>>>(pre_x, pre_y, xyenc);
    pack_dec_k<<<1152, 256, 0, stream>>>(fx, xdec, 48 * 16 * 6 * 64);

    int cur = 0;
    // --- encode: 64 steps ---
    for (int t = 0; t < 64; ++t) {
        lstm_cell_k<<<dim3(64, 4), 256, 0, stream>>>(
            xyenc + (size_t)t * 65536, 8, wih0, h0b[cur], whh0, b0s, c0, h0b[1 - cur]);
        lstm_cell_k<<<dim3(64, 4), 256, 0, stream>>>(
            h0b[1 - cur], 32, wih1, h1b[cur], whh1, b1s, c1, h1b[1 - cur]);
        cur ^= 1;
    }
    // --- decode: 48 steps ---
    float* out = (float*)d_out;
    for (int t = 0; t < 48; ++t) {
        fc1_k<<<dim3(16, 4), 256, 0, stream>>>(h1b[cur], fcw1, fc_b1, ufc);
        fc2_k<<<16, 256, 0, stream>>>(ufc, fcw2, fc_b2, estp,
                                      out + (size_t)t * 16384,
                                      xdec + (size_t)t * 65536);
        lstm_cell_k<<<dim3(64, 4), 256, 0, stream>>>(
            xdec + (size_t)t * 65536, 8, wih0, h0b[cur], whh0, b0s, c0, h0b[1 - cur]);
        lstm_cell_k<<<dim3(64, 4), 256, 0, stream>>>(
            h0b[1 - cur], 32, wih1, h1b[cur], whh1, b1s, c1, h1b[1 - cur]);
        cur ^= 1;
    }
}